// Round 5
// baseline (30.720 us; speedup 1.0000x reference)
//
#include <hip/hip_runtime.h>
#include <math.h>

// RBF layer: out[b,u] = exp(-gamma*||x_b - c_u||^2), B=8192, U=2048, DIM=32, f32.
//
// out = exp2(kg*||x||^2 + kg*||c||^2 + m2*(x.c)); x.c via bf16 hi/lo split
// (3x mfma_f32_16x16x32_bf16, K=32=DIM). Norms in full f32. Dropped lo*lo
// term ~2e-4 in exponent -> output error ~1e-7 << 4.56e-6 threshold.
//
// R4 diagnosis: write-efficiency-bound. MFMA C layout (col=lane&15) made each
// store instr scatter 4x64B segments -> 2.4 TB/s effective vs 6.3 TB/s for
// wave-contiguous writes (harness fills). R5 fix: LDS-bounce epilogue -
// exp results to s_o[64][132] (pad 4 -> 2-way bank alias = free), barrier,
// then global_store_dwordx4 with lanes covering contiguous 512B row runs.

#define BATCH   8192
#define UNITS   2048
#define DIM     32
#define BM      64
#define BN      128
#define THREADS 256

typedef __attribute__((ext_vector_type(8))) short s16x8;   // 8 bf16
typedef __attribute__((ext_vector_type(4))) float f32x4;

static __device__ __forceinline__ unsigned bf16_rne(float v) {
    unsigned u = __builtin_bit_cast(unsigned, v);
    return (u + 0x7FFFu + ((u >> 16) & 1u)) >> 16;   // round-to-nearest-even
}

// Load 8 consecutive f32 and split each into bf16 hi + bf16 lo.
static __device__ __forceinline__ void load_split(const float* __restrict__ p,
                                                  s16x8& hi, s16x8& lo) {
    float4 a = *reinterpret_cast<const float4*>(p);
    float4 b = *reinterpret_cast<const float4*>(p + 4);
    float v[8] = {a.x, a.y, a.z, a.w, b.x, b.y, b.z, b.w};
#pragma unroll
    for (int j = 0; j < 8; ++j) {
        unsigned h = bf16_rne(v[j]);
        float hf = __builtin_bit_cast(float, h << 16);
        unsigned l = bf16_rne(v[j] - hf);
        hi[j] = (short)h;
        lo[j] = (short)l;
    }
}

__global__ __launch_bounds__(THREADS) void rbf_mfma(
    const float* __restrict__ x,
    const float* __restrict__ centers,
    const float* __restrict__ gamma,
    float* __restrict__ out)
{
    __shared__ __align__(16) float s_o[BM][BN + 4];  // output bounce tile (33.8 KB)
    __shared__ __align__(16) float s_xn[BM];         // kg * ||x_row||^2
    __shared__ __align__(16) float s_cn[BN];         // kg * ||c_col||^2

    const int tid = threadIdx.x;
    const int r0  = blockIdx.y * BM;
    const int c0  = blockIdx.x * BN;

    const float kg = -gamma[0] * 1.4426950408889634f;  // -g*log2(e)
    const float m2 = -2.0f * kg;

    // ---- norms prologue (full f32) ----
    if (tid < BM) {
        const float4* p = reinterpret_cast<const float4*>(x + (size_t)(r0 + tid) * DIM);
        float s = 0.f;
#pragma unroll
        for (int i = 0; i < DIM / 4; ++i) {
            float4 t = p[i];
            s = fmaf(t.x, t.x, s); s = fmaf(t.y, t.y, s);
            s = fmaf(t.z, t.z, s); s = fmaf(t.w, t.w, s);
        }
        s_xn[tid] = kg * s;
    } else if (tid < BM + BN) {
        const int cc = tid - BM;
        const float4* p = reinterpret_cast<const float4*>(centers + (size_t)(c0 + cc) * DIM);
        float s = 0.f;
#pragma unroll
        for (int i = 0; i < DIM / 4; ++i) {
            float4 t = p[i];
            s = fmaf(t.x, t.x, s); s = fmaf(t.y, t.y, s);
            s = fmaf(t.z, t.z, s); s = fmaf(t.w, t.w, s);
        }
        s_cn[cc] = kg * s;
    }

    const int wid  = tid >> 6;        // wave 0..3
    const int lane = tid & 63;
    const int wm   = wid >> 1;        // wave M index 0..1
    const int wn   = wid & 1;         // wave N index 0..1
    const int l16  = lane & 15;
    const int kq   = lane >> 4;       // 0..3

    // ---- A fragments: 2 M-tiles of x ----
    s16x8 a_hi[2], a_lo[2];
#pragma unroll
    for (int m = 0; m < 2; ++m) {
        const float* p = x + (size_t)(r0 + wm * 32 + m * 16 + l16) * DIM + kq * 8;
        load_split(p, a_hi[m], a_lo[m]);
    }
    // ---- B fragments: 4 N-tiles of centers ----
    s16x8 b_hi[4], b_lo[4];
#pragma unroll
    for (int n = 0; n < 4; ++n) {
        const float* p = centers + (size_t)(c0 + wn * 64 + n * 16 + l16) * DIM + kq * 8;
        load_split(p, b_hi[n], b_lo[n]);
    }

    __syncthreads();   // s_xn/s_cn ready

    // ---- per-lane row norms ----
    float xnq[2][4];
#pragma unroll
    for (int m = 0; m < 2; ++m) {
        const int base = wm * 32 + m * 16 + kq * 4;
#pragma unroll
        for (int j = 0; j < 4; ++j) xnq[m][j] = s_xn[base + j];
    }

    // ---- MFMA + exp -> LDS bounce tile ----
#pragma unroll
    for (int m = 0; m < 2; ++m) {
#pragma unroll
        for (int n = 0; n < 4; ++n) {
            f32x4 acc = {0.f, 0.f, 0.f, 0.f};
            acc = __builtin_amdgcn_mfma_f32_16x16x32_bf16(a_lo[m], b_hi[n], acc, 0, 0, 0);
            acc = __builtin_amdgcn_mfma_f32_16x16x32_bf16(a_hi[m], b_lo[n], acc, 0, 0, 0);
            acc = __builtin_amdgcn_mfma_f32_16x16x32_bf16(a_hi[m], b_hi[n], acc, 0, 0, 0);

            const int col   = wn * 64 + n * 16 + l16;
            const float cnv = s_cn[col];
            const int row   = wm * 32 + m * 16 + kq * 4;
#pragma unroll
            for (int j = 0; j < 4; ++j) {
                float e = fmaf(m2, acc[j], xnq[m][j] + cnv);
                s_o[row + j][col] = __builtin_amdgcn_exp2f(e);
            }
        }
    }

    __syncthreads();   // bounce tile ready

    // ---- coalesced store pass: 8x global_store_dwordx4 per thread ----
    const int c4 = tid & 31;          // float4 column 0..31
    const int rb = tid >> 5;          // row base 0..7
#pragma unroll
    for (int i = 0; i < 8; ++i) {
        const int row = rb + i * 8;
        float4 v = *reinterpret_cast<const float4*>(&s_o[row][c4 * 4]);
        *reinterpret_cast<float4*>(out + (size_t)(r0 + row) * UNITS + c0 + c4 * 4) = v;
    }
}

extern "C" void kernel_launch(void* const* d_in, const int* in_sizes, int n_in,
                              void* d_out, int out_size, void* d_ws, size_t ws_size,
                              hipStream_t stream)
{
    const float* x       = (const float*)d_in[0];
    const float* centers = (const float*)d_in[1];
    const float* gamma   = (const float*)d_in[2];
    float* out           = (float*)d_out;

    dim3 grid(UNITS / BN, BATCH / BM);   // (16, 128) = 2048 blocks
    dim3 block(THREADS);
    rbf_mfma<<<grid, block, 0, stream>>>(x, centers, gamma, out);
}

// Round 6
// 21.412 us; speedup vs baseline: 1.4347x; 1.4347x over previous
//
#include <hip/hip_runtime.h>
#include <math.h>

// RBF layer: out[b,u] = exp(-gamma*||x_b - c_u||^2), B=8192, U=2048, DIM=32, f32.
//
// out = exp2(kg*||x||^2 + kg*||c||^2 + m2*(x.c)); x.c via bf16 hi/lo split
// (3x mfma_f32_16x16x32_bf16, K=32=DIM). Norms full f32. Verified R4/R5.
//
// R5 post-mortem: store pattern irrelevant (R4 scatter == R5 coalesced).
// Bottleneck = 2048 short-lived blocks (prologue+barriers per 32KB output).
// R6: persistent streaming kernel. 512 blocks (16 col x 32 row), each loops
// 4 row-tiles. Centers loaded once. NO barriers, NO LDS:
//  - norms via shfl_xor(16/32) over the 4 kq-lanes sharing a row.
//  - MFMA operands SWAPPED: D = c . x^T, so lane holds 4 consecutive unit
//    columns for one x-row -> global_store_dwordx4, and the per-iter row
//    norm is the lane's own reduced value (no cross-lane in the loop).
//  - x loads software-pipelined one iteration ahead (ping-pong regs).

#define BATCH   8192
#define UNITS   2048
#define DIM     32
#define BM      64
#define BN      128
#define THREADS 256
#define GRIDY   32
#define ITERS   4      // GRIDY * ITERS * BM == BATCH

typedef __attribute__((ext_vector_type(8))) short s16x8;   // 8 bf16
typedef __attribute__((ext_vector_type(4))) float f32x4;

static __device__ __forceinline__ unsigned bf16_rne(float v) {
    unsigned u = __builtin_bit_cast(unsigned, v);
    return (u + 0x7FFFu + ((u >> 16) & 1u)) >> 16;   // round-to-nearest-even
}

static __device__ __forceinline__ void load8(const float* __restrict__ p, float* v) {
    float4 t0 = *reinterpret_cast<const float4*>(p);
    float4 t1 = *reinterpret_cast<const float4*>(p + 4);
    v[0] = t0.x; v[1] = t0.y; v[2] = t0.z; v[3] = t0.w;
    v[4] = t1.x; v[5] = t1.y; v[6] = t1.z; v[7] = t1.w;
}

static __device__ __forceinline__ void split8(const float* v, s16x8& hi, s16x8& lo) {
#pragma unroll
    for (int j = 0; j < 8; ++j) {
        unsigned h = bf16_rne(v[j]);
        float hf = __builtin_bit_cast(float, h << 16);
        unsigned l = bf16_rne(v[j] - hf);
        hi[j] = (short)h;
        lo[j] = (short)l;
    }
}

__global__ __launch_bounds__(THREADS) void rbf_stream(
    const float* __restrict__ x,
    const float* __restrict__ centers,
    const float* __restrict__ gamma,
    float* __restrict__ out)
{
    const int tid  = threadIdx.x;
    const int wid  = tid >> 6;
    const int lane = tid & 63;
    const int wm   = wid >> 1;        // wave M index 0..1 (32 rows each)
    const int wn   = wid & 1;         // wave N index 0..1 (64 cols each)
    const int l16  = lane & 15;
    const int kq   = lane >> 4;       // 0..3

    const float kg = -gamma[0] * 1.4426950408889634f;  // -g*log2(e)
    const float m2 = -2.0f * kg;

    const int c0 = blockIdx.x * BN;

    // ---- prologue (once per block): center fragments + kg*||c||^2 ----
    s16x8 b_hi[4], b_lo[4];
    float kgcnq[4][4];                // [n][j]: kg*||c_{n*16+kq*4+j}||^2
#pragma unroll
    for (int n = 0; n < 4; ++n) {
        float v[8];
        load8(centers + (size_t)(c0 + wn * 64 + n * 16 + l16) * DIM + kq * 8, v);
        split8(v, b_hi[n], b_lo[n]);
        float pn = 0.f;
#pragma unroll
        for (int j = 0; j < 8; ++j) pn = fmaf(v[j], v[j], pn);
        pn += __shfl_xor(pn, 16);
        pn += __shfl_xor(pn, 32);     // lane now holds ||c_{l16}||^2 of tile n
#pragma unroll
        for (int j = 0; j < 4; ++j)
            kgcnq[n][j] = kg * __shfl(pn, kq * 4 + j);
    }

    // ---- row-tile loop, software-pipelined x loads ----
    float xf[2][2][8];                // [buf][m][elem]
    {
        const int r0 = blockIdx.y * BM;
#pragma unroll
        for (int m = 0; m < 2; ++m)
            load8(x + (size_t)(r0 + wm * 32 + m * 16 + l16) * DIM + kq * 8, xf[0][m]);
    }

#pragma unroll
    for (int k = 0; k < ITERS; ++k) {
        const int cur = k & 1;
        const int r0  = (blockIdx.y + k * GRIDY) * BM;

        if (k + 1 < ITERS) {          // prefetch next tile into other buffer
            const int r1 = (blockIdx.y + (k + 1) * GRIDY) * BM;
#pragma unroll
            for (int m = 0; m < 2; ++m)
                load8(x + (size_t)(r1 + wm * 32 + m * 16 + l16) * DIM + kq * 8,
                      xf[cur ^ 1][m]);
        }

        // convert + per-row norms (wave-local, no LDS)
        s16x8 a_hi[2], a_lo[2];
        float kgxn[2];
#pragma unroll
        for (int m = 0; m < 2; ++m) {
            split8(xf[cur][m], a_hi[m], a_lo[m]);
            float pn = 0.f;
#pragma unroll
            for (int j = 0; j < 8; ++j) pn = fmaf(xf[cur][m][j], xf[cur][m][j], pn);
            pn += __shfl_xor(pn, 16);
            pn += __shfl_xor(pn, 32); // full kg-less norm of row l16 (tile m)
            kgxn[m] = kg * pn;
        }

        // MFMA (swapped: D = c . x^T) + epilogue with dwordx4 stores
#pragma unroll
        for (int m = 0; m < 2; ++m) {
#pragma unroll
            for (int n = 0; n < 4; ++n) {
                f32x4 acc = {0.f, 0.f, 0.f, 0.f};
                acc = __builtin_amdgcn_mfma_f32_16x16x32_bf16(b_lo[n], a_hi[m], acc, 0, 0, 0);
                acc = __builtin_amdgcn_mfma_f32_16x16x32_bf16(b_hi[n], a_lo[m], acc, 0, 0, 0);
                acc = __builtin_amdgcn_mfma_f32_16x16x32_bf16(b_hi[n], a_hi[m], acc, 0, 0, 0);

                float4 o;
                o.x = __builtin_amdgcn_exp2f(fmaf(m2, acc[0], kgxn[m] + kgcnq[n][0]));
                o.y = __builtin_amdgcn_exp2f(fmaf(m2, acc[1], kgxn[m] + kgcnq[n][1]));
                o.z = __builtin_amdgcn_exp2f(fmaf(m2, acc[2], kgxn[m] + kgcnq[n][2]));
                o.w = __builtin_amdgcn_exp2f(fmaf(m2, acc[3], kgxn[m] + kgcnq[n][3]));

                float* op = out + (size_t)(r0 + wm * 32 + m * 16 + l16) * UNITS
                                + (c0 + wn * 64 + n * 16 + kq * 4);
                *reinterpret_cast<float4*>(op) = o;
            }
        }
    }
}

extern "C" void kernel_launch(void* const* d_in, const int* in_sizes, int n_in,
                              void* d_out, int out_size, void* d_ws, size_t ws_size,
                              hipStream_t stream)
{
    const float* x       = (const float*)d_in[0];
    const float* centers = (const float*)d_in[1];
    const float* gamma   = (const float*)d_in[2];
    float* out           = (float*)d_out;

    dim3 grid(UNITS / BN, GRIDY);     // (16, 32) = 512 persistent-ish blocks
    dim3 block(THREADS);
    rbf_stream<<<grid, block, 0, stream>>>(x, centers, gamma, out);
}